// Round 3
// baseline (703.111 us; speedup 1.0000x reference)
//
#include <hip/hip_runtime.h>
#include <cstdint>
#include <cstddef>

#define PI_F 3.14159265358979323846f

constexpr int BB = 4, NN = 512, BN = 2048, NBIN = 48;

// ---------------------------------------------------------------- prep
// F0: [2048][48] = (v1, other(3), v0_enc(16)) vector channels, padded 40->48 with zeros
__global__ void prep_kernel(const float* __restrict__ p0, const float* __restrict__ v0,
                            const float* __restrict__ a, const float* __restrict__ other,
                            const float* __restrict__ v0enc,
                            float* __restrict__ p1, float* __restrict__ F0) {
  int n = blockIdx.x * blockDim.x + threadIdx.x;
  if (n >= BN) return;
  float p0x = p0[n*2], p0y = p0[n*2+1];
  float v0x = v0[n*2], v0y = v0[n*2+1];
  float ax = a[n*2],  ay = a[n*2+1];
  float v1x = v0x + 0.1f*ax, v1y = v0y + 0.1f*ay;
  float p1x = p0x + 0.1f*(v0x+v1x)*0.5f;
  float p1y = p0y + 0.1f*(v0y+v1y)*0.5f;
  p1[n*2] = p1x; p1[n*2+1] = p1y;
  float* F = F0 + (size_t)n*48;
  F[0] = v1x; F[1] = v1y;
  for (int c = 0; c < 3; ++c) {
    F[2+c*2]   = other[(n*3+c)*2];
    F[2+c*2+1] = other[(n*3+c)*2+1];
  }
  for (int c = 0; c < 16; ++c) {
    F[8+c*2]   = v0enc[(n*16+c)*2];
    F[8+c*2+1] = v0enc[(n*16+c)*2+1];
  }
  for (int c = 40; c < 48; ++c) F[c] = 0.0f;
}

// ---------------------------------------------------------------- steer
// K2 row ((k*Ipad + i)*2 + v), col o*2+u. Pad rows (i>=I) written as zeros.
__global__ void steer_kernel(const float* __restrict__ W, float* __restrict__ K2,
                             int O, int I, int Ipad) {
  int idx = blockIdx.x * blockDim.x + threadIdx.x;
  int total = NBIN * O * Ipad;
  if (idx >= total) return;
  int i = idx % Ipad;
  int o = (idx / Ipad) % O;
  int k = idx / (Ipad * O);
  int CTc = O * 2;
  size_t r0 = (size_t)((k*Ipad + i)*2 + 0) * CTc + o*2;
  size_t r1 = r0 + CTc;
  if (i >= I) {
    K2[r0] = 0.0f; K2[r0+1] = 0.0f; K2[r1] = 0.0f; K2[r1+1] = 0.0f;
    return;
  }
  int tt = k % 16;
  float ang = (tt + 0.5f) * (2.0f * PI_F / 16.0f) - PI_F;
  float ct = cosf(ang), st = sinf(ang);
  const float* Wp = W + ((size_t)(k*O + o)*I + i) * 4;
  float w00 = Wp[0], w01 = Wp[1], w10 = Wp[2], w11 = Wp[3];
  float rw00 = ct*w00 - st*w10, rw01 = ct*w01 - st*w11;
  float rw10 = st*w00 + ct*w10, rw11 = st*w01 + ct*w11;
  float k00 = rw00*ct - rw01*st;
  float k01 = rw00*st + rw01*ct;
  float k10 = rw10*ct - rw11*st;
  float k11 = rw10*st + rw11*ct;
  K2[r0 + 0] = k00; K2[r0 + 1] = k10;
  K2[r1 + 0] = k01; K2[r1 + 1] = k11;
}

// ---------------------------------------------------------------- pairs + compaction
__global__ __launch_bounds__(256) void pairs_compact(const float* __restrict__ qry,
                                                     const float* __restrict__ src,
                                                     const float* __restrict__ mask,
                                                     float* __restrict__ wlist,
                                                     int* __restrict__ plist,
                                                     int* __restrict__ cnt) {
  int wv = threadIdx.x >> 6;
  int lane = threadIdx.x & 63;
  int q = blockIdx.x * 4 + wv;
  int b = q >> 9;
  float qx = qry[q*2], qy = qry[q*2+1];
  const float* sb = src + b*1024;
  const float* mb = mask + (size_t)q*512;
  float* wl = wlist + (size_t)q*512;
  int* pl = plist + (size_t)q*512;
  int base = 0;
  for (int ch = 0; ch < 8; ++ch) {
    int s = ch*64 + lane;
    float sx = sb[s*2], sy = sb[s*2+1];
    float rx = sx - qx, ry = sy - qy;
    float d2 = rx*rx + ry*ry;
    float m = mb[s];
    float wi = fmaxf(1.0f - d2 / 1600.0f, 0.0f);
    float w = wi*wi*wi*m;
    bool pred = w > 0.0f;
    int k = 0;
    if (pred) {
      float dist = sqrtf(d2 + 1e-9f);
      float theta = atan2f(ry, rx);
      int rb = (int)(dist / 40.0f * 3.0f);
      rb = rb > 2 ? 2 : rb;
      float u = (theta + PI_F) / (2.0f * PI_F) * 16.0f;
      int tb = ((int)floorf(u)) & 15;
      k = rb*16 + tb;
    }
    unsigned long long msk = __ballot(pred);
    int before = __popcll(msk & ((1ull<<lane)-1ull));
    if (pred) {
      wl[base + before] = w;
      pl[base + before] = (s<<6) | k;
    }
    base += __popcll(msk);
  }
  if (lane == 0) cnt[q] = base;
}

// ---------------------------------------------------------------- accumulate M
// lists staged in LDS; 4 independent feature loads in flight per thread; ds_add scatter
template<int C2, int TPB>
__global__ __launch_bounds__(TPB) void accum3(const float* __restrict__ wlist,
                                              const int* __restrict__ plist,
                                              const int* __restrict__ cnt,
                                              const float* __restrict__ feats,
                                              float* __restrict__ Mout) {
  constexpr int Kd = NBIN * C2;
  constexpr int G = TPB / C2;
  static_assert(TPB % C2 == 0, "TPB multiple of C2");
  __shared__ float Ml[Kd];
  __shared__ float wsh[512];
  __shared__ int   psh[512];
  const int q = blockIdx.x;
  const int t = threadIdx.x;
  const int nnz = cnt[q];
  const float4* wl4 = (const float4*)(wlist + (size_t)q * 512);
  const int4*   pl4 = (const int4*)(plist + (size_t)q * 512);
  const int n4 = (nnz + 3) >> 2;
  for (int i = t; i < n4; i += TPB) {
    ((float4*)wsh)[i] = wl4[i];
    ((int4*)psh)[i]   = pl4[i];
  }
  for (int i = t; i < Kd; i += TPB) Ml[i] = 0.0f;
  __syncthreads();
  const int g = t / C2, c = t % C2;
  const float* fb = feats + (size_t)(q >> 9) * 512 * C2 + c;
  int e = g;
  for (; e + 3*G < nnz; e += 4*G) {
    float w0 = wsh[e];       int p0 = psh[e];
    float w1 = wsh[e+G];     int p1 = psh[e+G];
    float w2 = wsh[e+2*G];   int p2 = psh[e+2*G];
    float w3 = wsh[e+3*G];   int p3 = psh[e+3*G];
    float f0 = fb[(p0 >> 6) * C2];
    float f1 = fb[(p1 >> 6) * C2];
    float f2 = fb[(p2 >> 6) * C2];
    float f3 = fb[(p3 >> 6) * C2];
    __hip_atomic_fetch_add(&Ml[(p0 & 63)*C2 + c], w0*f0, __ATOMIC_RELAXED, __HIP_MEMORY_SCOPE_WORKGROUP);
    __hip_atomic_fetch_add(&Ml[(p1 & 63)*C2 + c], w1*f1, __ATOMIC_RELAXED, __HIP_MEMORY_SCOPE_WORKGROUP);
    __hip_atomic_fetch_add(&Ml[(p2 & 63)*C2 + c], w2*f2, __ATOMIC_RELAXED, __HIP_MEMORY_SCOPE_WORKGROUP);
    __hip_atomic_fetch_add(&Ml[(p3 & 63)*C2 + c], w3*f3, __ATOMIC_RELAXED, __HIP_MEMORY_SCOPE_WORKGROUP);
  }
  for (; e < nnz; e += G) {
    float w = wsh[e]; int p = psh[e];
    float f = fb[(p >> 6) * C2];
    __hip_atomic_fetch_add(&Ml[(p & 63)*C2 + c], w*f, __ATOMIC_RELAXED, __HIP_MEMORY_SCOPE_WORKGROUP);
  }
  __syncthreads();
  float4* M4o = (float4*)(Mout + (size_t)q * Kd);
  const float4* M4 = (const float4*)Ml;
  for (int i = t; i < Kd/4; i += TPB) M4o[i] = M4[i];
}

// ---------------------------------------------------------------- tiled fp32 GEMM with k-split
template<int CT>
__global__ __launch_bounds__(256) void gemm_tiled(const float* __restrict__ A,
                                                  const float* __restrict__ B,
                                                  float* __restrict__ G, int Kdim, int kps) {
  __shared__ float At[16][64];
  __shared__ float Bt[16][CT];
  const int t = threadIdx.x;
  const int row0 = blockIdx.x * 64;
  const int kbeg = blockIdx.y * kps;
  constexpr int CQ = CT / 4;
  constexpr int RGN = 256 / CQ;
  constexpr int RPT = 64 / RGN;
  const int cq = t % CQ;
  const int rg = t / CQ;
  float acc[RPT][4];
  #pragma unroll
  for (int r = 0; r < RPT; ++r)
    for (int cc = 0; cc < 4; ++cc) acc[r][cc] = 0.0f;
  const int arow = t >> 2, akq = t & 3;
  for (int kt = 0; kt < kps; kt += 16) {
    const int k0 = kbeg + kt;
    float4 av4 = *(const float4*)(A + (size_t)(row0 + arow) * Kdim + (k0 + akq*4));
    At[akq*4+0][arow] = av4.x;
    At[akq*4+1][arow] = av4.y;
    At[akq*4+2][arow] = av4.z;
    At[akq*4+3][arow] = av4.w;
    if (CT == 64) {
      int kk = t >> 4, col = (t & 15) * 4;
      *(float4*)&Bt[kk][col] = *(const float4*)(B + (size_t)(k0+kk)*CT + col);
    } else if (t < 128) {
      int kk = t >> 3, col = (t & 7) * 4;
      *(float4*)&Bt[kk][col] = *(const float4*)(B + (size_t)(k0+kk)*CT + col);
    }
    __syncthreads();
    #pragma unroll
    for (int kk = 0; kk < 16; ++kk) {
      float4 bv = *(const float4*)&Bt[kk][cq*4];
      if (RPT == 4) {
        float4 a4 = *(const float4*)&At[kk][rg*4];
        acc[0][0] += a4.x*bv.x; acc[0][1] += a4.x*bv.y; acc[0][2] += a4.x*bv.z; acc[0][3] += a4.x*bv.w;
        acc[1][0] += a4.y*bv.x; acc[1][1] += a4.y*bv.y; acc[1][2] += a4.y*bv.z; acc[1][3] += a4.y*bv.w;
        acc[2][0] += a4.z*bv.x; acc[2][1] += a4.z*bv.y; acc[2][2] += a4.z*bv.z; acc[2][3] += a4.z*bv.w;
        acc[3][0] += a4.w*bv.x; acc[3][1] += a4.w*bv.y; acc[3][2] += a4.w*bv.z; acc[3][3] += a4.w*bv.w;
      } else {
        float2 a2 = *(const float2*)&At[kk][rg*2];
        acc[0][0] += a2.x*bv.x; acc[0][1] += a2.x*bv.y; acc[0][2] += a2.x*bv.z; acc[0][3] += a2.x*bv.w;
        acc[1][0] += a2.y*bv.x; acc[1][1] += a2.y*bv.y; acc[1][2] += a2.y*bv.z; acc[1][3] += a2.y*bv.w;
      }
    }
    __syncthreads();
  }
  const size_t zoff = (size_t)blockIdx.y * BN;
  for (int r = 0; r < RPT; ++r) {
    int row = row0 + rg*RPT + r;
    float* gp = G + (zoff + row) * CT + cq*4;
    gp[0] = acc[r][0]; gp[1] = acc[r][1]; gp[2] = acc[r][2]; gp[3] = acc[r][3];
  }
}

// ---------------------------------------------------------------- thin GEMM for layer4 (2 cols)
__global__ __launch_bounds__(256) void gemm_thin2(const float* __restrict__ M,
                                                  const float* __restrict__ K2,
                                                  float* __restrict__ out) {
  int lane = threadIdx.x & 63;
  int wv = threadIdx.x >> 6;
  int row = blockIdx.x * 4 + wv;
  const float* Ar = M + (size_t)row * 3072;
  float a0 = 0.0f, a1 = 0.0f;
  for (int k = lane; k < 3072; k += 64) {
    float av = Ar[k];
    a0 += av * K2[k*2];
    a1 += av * K2[k*2+1];
  }
  for (int off = 32; off > 0; off >>= 1) {
    a0 += __shfl_down(a0, off);
    a1 += __shfl_down(a1, off);
  }
  if (lane == 0) { out[row*2] = a0; out[row*2+1] = a1; }
}

// ---------------------------------------------------------------- stage-0 epilogue
__global__ void epilogue0(const float* __restrict__ Gpf, const float* __restrict__ Gpo,
                          const float* __restrict__ F0, const float* __restrict__ Adf,
                          const float* __restrict__ Bdf, float* __restrict__ in1) {
  int idx = blockIdx.x * blockDim.x + threadIdx.x;  // q*48+ch
  if (idx >= BN*48) return;
  int ch = idx % 48, q = idx / 48;
  float x = 0.0f, y = 0.0f;
  if (ch < 16) {
    for (int sp = 0; sp < 6; ++sp) {
      size_t base = ((size_t)sp*BN + q)*32 + ch*2;
      x += Gpo[base]; y += Gpo[base+1];
    }
  } else if (ch < 32) {
    int o = ch - 16;
    for (int sp = 0; sp < 8; ++sp) {
      size_t base = ((size_t)sp*BN + q)*32 + o*2;
      x += Gpf[base]; y += Gpf[base+1];
    }
  } else {
    int o = ch - 32;
    const float* f = F0 + (size_t)q*48;
    for (int i = 0; i < 20; ++i) {
      float fx = f[i*2], fy = f[i*2+1];
      float Av = Adf[o*20+i], Bv = Bdf[o*20+i];
      x += Av*fx - Bv*fy;
      y += Av*fy + Bv*fx;
    }
  }
  float m = x*x + y*y + 1e-6f;
  float sc = fmaxf(m - 0.2f, 0.0f) / m;
  in1[(size_t)idx*2]   = x * sc;
  in1[(size_t)idx*2+1] = y * sc;
}

// ---------------------------------------------------------------- layer epilogue (layers 1-3)
__global__ void epilogueL(const float* __restrict__ Gp, int SPLIT,
                          const float* __restrict__ inPrev, int I,
                          const float* __restrict__ Ad, const float* __restrict__ Bd,
                          const float* __restrict__ prevOut, int doRes,
                          float* __restrict__ outCur, float* __restrict__ inNext) {
  int idx = blockIdx.x * blockDim.x + threadIdx.x;  // q*32+o
  if (idx >= BN*32) return;
  int o = idx % 32, q = idx / 32;
  float x = 0.0f, y = 0.0f;
  for (int sp = 0; sp < SPLIT; ++sp) {
    size_t base = ((size_t)sp*BN + q)*64 + o*2;
    x += Gp[base]; y += Gp[base+1];
  }
  const float* f = inPrev + (size_t)q * I * 2;
  for (int i = 0; i < I; ++i) {
    float fx = f[i*2], fy = f[i*2+1];
    float Av = Ad[o*I+i], Bv = Bd[o*I+i];
    x += Av*fx - Bv*fy;
    y += Av*fy + Bv*fx;
  }
  if (doRes) {
    x += prevOut[(size_t)idx*2];
    y += prevOut[(size_t)idx*2+1];
  }
  outCur[(size_t)idx*2]   = x;
  outCur[(size_t)idx*2+1] = y;
  float m = x*x + y*y + 1e-6f;
  float sc = fmaxf(m - 0.2f, 0.0f) / m;
  inNext[(size_t)idx*2]   = x * sc;
  inNext[(size_t)idx*2+1] = y * sc;
}

// ---------------------------------------------------------------- final
__global__ void final_kernel(const float* __restrict__ conv4, const float* __restrict__ in4,
                             const float* __restrict__ Ad4, const float* __restrict__ Bd4,
                             const float* __restrict__ p1, const float* __restrict__ p0,
                             float* __restrict__ dout) {
  int q = blockIdx.x * blockDim.x + threadIdx.x;
  if (q >= BN) return;
  float x = conv4[q*2], y = conv4[q*2+1];
  const float* f = in4 + (size_t)q * 64;
  for (int i = 0; i < 32; ++i) {
    float fx = f[i*2], fy = f[i*2+1];
    float Av = Ad4[i], Bv = Bd4[i];
    x += Av*fx - Bv*fy;
    y += Av*fy + Bv*fx;
  }
  float cx = x / 128.0f, cy = y / 128.0f;
  float px = p1[q*2] + cx, py = p1[q*2+1] + cy;
  float vx = (px - p0[q*2]) / 0.1f;
  float vy = (py - p0[q*2+1]) / 0.1f;
  dout[q*2] = px; dout[q*2+1] = py;
  dout[4096 + q*2] = vx; dout[4096 + q*2+1] = vy;
}

// ---------------------------------------------------------------- launch
extern "C" void kernel_launch(void* const* d_in, const int* in_sizes, int n_in,
                              void* d_out, int out_size, void* d_ws, size_t ws_size,
                              hipStream_t stream) {
  (void)in_sizes; (void)n_in; (void)out_size; (void)ws_size;
  const float* v0_enc = (const float*)d_in[1];
  const float* p0     = (const float*)d_in[2];
  const float* v0     = (const float*)d_in[3];
  const float* a      = (const float*)d_in[4];
  const float* other  = (const float*)d_in[5];
  const float* box    = (const float*)d_in[6];
  const float* boxf   = (const float*)d_in[7];
  const float* fmask  = (const float*)d_in[8];
  const float* bmask  = (const float*)d_in[9];
  const float* Wcf = (const float*)d_in[10];
  const float* Wco = (const float*)d_in[11];
  const float* Adf = (const float*)d_in[12];
  const float* Bdf = (const float*)d_in[13];
  const float* Wc1 = (const float*)d_in[14];
  const float* Ad1 = (const float*)d_in[15];
  const float* Bd1 = (const float*)d_in[16];
  const float* Wc2 = (const float*)d_in[17];
  const float* Ad2 = (const float*)d_in[18];
  const float* Bd2 = (const float*)d_in[19];
  const float* Wc3 = (const float*)d_in[20];
  const float* Ad3 = (const float*)d_in[21];
  const float* Bd3 = (const float*)d_in[22];
  const float* Wc4 = (const float*)d_in[23];
  const float* Ad4 = (const float*)d_in[24];
  const float* Bd4 = (const float*)d_in[25];

  float* ws = (float*)d_ws;
  float* P1    = ws + 0;          // 4096
  float* F0    = ws + 4096;       // 98304  (stride 48, padded)
  float* K2CF  = ws + 102400;     // 73728  (2304 x 32)
  float* K2CO  = ws + 176128;     // 3072   (96 x 32)
  float* K2C1  = ws + 179200;     // 294912 (4608 x 64)
  float* K2C2  = ws + 474112;     // 196608 (3072 x 64)
  float* K2C3  = ws + 670720;     // 196608
  float* K2C4  = ws + 867328;     // 6144   (3072 x 2)
  float* WFl   = ws + 873472;     // 1048576
  int*   PFl   = (int*)(ws + 1922048);   // 1048576
  int*   CNTF  = (int*)(ws + 2970624);   // 2048
  int*   CNTO  = (int*)(ws + 2972672);   // 2048
  float* IN1   = ws + 2974720;    // 196608 (2048 x 96)
  float* IN2   = ws + 3171328;    // 131072
  float* IN3   = ws + 3302400;    // 131072
  float* IN4   = ws + 3433472;    // 131072
  float* OUTA  = ws + 3564544;    // 131072
  float* OUTB  = ws + 3695616;    // 131072
  float* C4OUT = ws + 3826688;    // 4096
  float* MO    = ws + 3830784;    // 196608 (box M: 2048 x 96)
  float* GPF   = ws + 4027392;    // 524288 (8 x 2048 x 32)
  float* GPO   = ws + 4551680;    // 393216 (6 x 2048 x 32)
  float* GPART = ws + 4027392;    // 1048576 (8 x 2048 x 64) reuses GPF/GPO region
  float* MBUF  = ws + 5075968;    // 9437184 (max 2048 x 4608)
  float* WOl   = MBUF + 7340032;  // 1048576 (dead before layer1 M reaches here)
  int*   POl   = (int*)(MBUF + 8388608);  // 1048576

  prep_kernel<<<8, 256, 0, stream>>>(p0, v0, a, other, v0_enc, P1, F0);
  steer_kernel<<<(48*16*24 + 255)/256, 256, 0, stream>>>(Wcf, K2CF, 16, 20, 24);
  steer_kernel<<<(48*16*1  + 255)/256, 256, 0, stream>>>(Wco, K2CO, 16, 1, 1);
  steer_kernel<<<(48*32*48 + 255)/256, 256, 0, stream>>>(Wc1, K2C1, 32, 48, 48);
  steer_kernel<<<(48*32*32 + 255)/256, 256, 0, stream>>>(Wc2, K2C2, 32, 32, 32);
  steer_kernel<<<(48*32*32 + 255)/256, 256, 0, stream>>>(Wc3, K2C3, 32, 32, 32);
  steer_kernel<<<(48*1*32  + 255)/256, 256, 0, stream>>>(Wc4, K2C4, 1, 32, 32);
  pairs_compact<<<512, 256, 0, stream>>>(P1, P1, fmask, WFl, PFl, CNTF);
  pairs_compact<<<512, 256, 0, stream>>>(P1, box, bmask, WOl, POl, CNTO);

  // stage 0
  accum3<2, 128><<<BN, 128, 0, stream>>>(WOl, POl, CNTO, boxf, MO);
  gemm_tiled<32><<<dim3(32, 6), 256, 0, stream>>>(MO, K2CO, GPO, 96, 16);
  accum3<48, 192><<<BN, 192, 0, stream>>>(WFl, PFl, CNTF, F0, MBUF);
  gemm_tiled<32><<<dim3(32, 8), 256, 0, stream>>>(MBUF, K2CF, GPF, 2304, 288);
  epilogue0<<<384, 256, 0, stream>>>(GPF, GPO, F0, Adf, Bdf, IN1);

  // layer 1: I=48 -> O=32
  accum3<96, 384><<<BN, 384, 0, stream>>>(WFl, PFl, CNTF, IN1, MBUF);
  gemm_tiled<64><<<dim3(32, 8), 256, 0, stream>>>(MBUF, K2C1, GPART, 4608, 576);
  epilogueL<<<256, 256, 0, stream>>>(GPART, 8, IN1, 48, Ad1, Bd1, nullptr, 0, OUTA, IN2);

  // layer 2: I=32 -> O=32, residual
  accum3<64, 256><<<BN, 256, 0, stream>>>(WFl, PFl, CNTF, IN2, MBUF);
  gemm_tiled<64><<<dim3(32, 8), 256, 0, stream>>>(MBUF, K2C2, GPART, 3072, 384);
  epilogueL<<<256, 256, 0, stream>>>(GPART, 8, IN2, 32, Ad2, Bd2, OUTA, 1, OUTB, IN3);

  // layer 3: I=32 -> O=32, residual
  accum3<64, 256><<<BN, 256, 0, stream>>>(WFl, PFl, CNTF, IN3, MBUF);
  gemm_tiled<64><<<dim3(32, 8), 256, 0, stream>>>(MBUF, K2C3, GPART, 3072, 384);
  epilogueL<<<256, 256, 0, stream>>>(GPART, 8, IN3, 32, Ad3, Bd3, OUTB, 1, OUTA, IN4);

  // layer 4: I=32 -> O=1, then apply correction
  accum3<64, 256><<<BN, 256, 0, stream>>>(WFl, PFl, CNTF, IN4, MBUF);
  gemm_thin2<<<512, 256, 0, stream>>>(MBUF, K2C4, C4OUT);
  final_kernel<<<8, 256, 0, stream>>>(C4OUT, IN4, Ad4, Bd4, P1, p0, (float*)d_out);
}

// Round 4
// 456.429 us; speedup vs baseline: 1.5405x; 1.5405x over previous
//
#include <hip/hip_runtime.h>
#include <cstdint>
#include <cstddef>

#define PI_F 3.14159265358979323846f

constexpr int BB = 4, NN = 512, BN = 2048, NBIN = 48;

// ---------------------------------------------------------------- prep
// F0: [2048][48] = (v1, other(3), v0_enc(16)) vector channels, padded 40->48 with zeros
__global__ void prep_kernel(const float* __restrict__ p0, const float* __restrict__ v0,
                            const float* __restrict__ a, const float* __restrict__ other,
                            const float* __restrict__ v0enc,
                            float* __restrict__ p1, float* __restrict__ F0) {
  int n = blockIdx.x * blockDim.x + threadIdx.x;
  if (n >= BN) return;
  float p0x = p0[n*2], p0y = p0[n*2+1];
  float v0x = v0[n*2], v0y = v0[n*2+1];
  float ax = a[n*2],  ay = a[n*2+1];
  float v1x = v0x + 0.1f*ax, v1y = v0y + 0.1f*ay;
  float p1x = p0x + 0.1f*(v0x+v1x)*0.5f;
  float p1y = p0y + 0.1f*(v0y+v1y)*0.5f;
  p1[n*2] = p1x; p1[n*2+1] = p1y;
  float* F = F0 + (size_t)n*48;
  F[0] = v1x; F[1] = v1y;
  for (int c = 0; c < 3; ++c) {
    F[2+c*2]   = other[(n*3+c)*2];
    F[2+c*2+1] = other[(n*3+c)*2+1];
  }
  for (int c = 0; c < 16; ++c) {
    F[8+c*2]   = v0enc[(n*16+c)*2];
    F[8+c*2+1] = v0enc[(n*16+c)*2+1];
  }
  for (int c = 40; c < 48; ++c) F[c] = 0.0f;
}

// ---------------------------------------------------------------- steer
// K2 row ((k*Ipad + i)*2 + v), col o*2+u. Pad rows (i>=I) written as zeros.
__global__ void steer_kernel(const float* __restrict__ W, float* __restrict__ K2,
                             int O, int I, int Ipad) {
  int idx = blockIdx.x * blockDim.x + threadIdx.x;
  int total = NBIN * O * Ipad;
  if (idx >= total) return;
  int i = idx % Ipad;
  int o = (idx / Ipad) % O;
  int k = idx / (Ipad * O);
  int CTc = O * 2;
  size_t r0 = (size_t)((k*Ipad + i)*2 + 0) * CTc + o*2;
  size_t r1 = r0 + CTc;
  if (i >= I) {
    K2[r0] = 0.0f; K2[r0+1] = 0.0f; K2[r1] = 0.0f; K2[r1+1] = 0.0f;
    return;
  }
  int tt = k % 16;
  float ang = (tt + 0.5f) * (2.0f * PI_F / 16.0f) - PI_F;
  float ct = cosf(ang), st = sinf(ang);
  const float* Wp = W + ((size_t)(k*O + o)*I + i) * 4;
  float w00 = Wp[0], w01 = Wp[1], w10 = Wp[2], w11 = Wp[3];
  float rw00 = ct*w00 - st*w10, rw01 = ct*w01 - st*w11;
  float rw10 = st*w00 + ct*w10, rw11 = st*w01 + ct*w11;
  float k00 = rw00*ct - rw01*st;
  float k01 = rw00*st + rw01*ct;
  float k10 = rw10*ct - rw11*st;
  float k11 = rw10*st + rw11*ct;
  K2[r0 + 0] = k00; K2[r0 + 1] = k10;
  K2[r1 + 0] = k01; K2[r1 + 1] = k11;
}

// ---------------------------------------------------------------- pairs + compaction
__global__ __launch_bounds__(256) void pairs_compact(const float* __restrict__ qry,
                                                     const float* __restrict__ src,
                                                     const float* __restrict__ mask,
                                                     float* __restrict__ wlist,
                                                     int* __restrict__ plist,
                                                     int* __restrict__ cnt) {
  int wv = threadIdx.x >> 6;
  int lane = threadIdx.x & 63;
  int q = blockIdx.x * 4 + wv;
  int b = q >> 9;
  float qx = qry[q*2], qy = qry[q*2+1];
  const float* sb = src + b*1024;
  const float* mb = mask + (size_t)q*512;
  float* wl = wlist + (size_t)q*512;
  int* pl = plist + (size_t)q*512;
  int base = 0;
  for (int ch = 0; ch < 8; ++ch) {
    int s = ch*64 + lane;
    float sx = sb[s*2], sy = sb[s*2+1];
    float rx = sx - qx, ry = sy - qy;
    float d2 = rx*rx + ry*ry;
    float m = mb[s];
    float wi = fmaxf(1.0f - d2 / 1600.0f, 0.0f);
    float w = wi*wi*wi*m;
    bool pred = w > 0.0f;
    int k = 0;
    if (pred) {
      float dist = sqrtf(d2 + 1e-9f);
      float theta = atan2f(ry, rx);
      int rb = (int)(dist / 40.0f * 3.0f);
      rb = rb > 2 ? 2 : rb;
      float u = (theta + PI_F) / (2.0f * PI_F) * 16.0f;
      int tb = ((int)floorf(u)) & 15;
      k = rb*16 + tb;
    }
    unsigned long long msk = __ballot(pred);
    int before = __popcll(msk & ((1ull<<lane)-1ull));
    if (pred) {
      wl[base + before] = w;
      pl[base + before] = (s<<6) | k;
    }
    base += __popcll(msk);
  }
  if (lane == 0) cnt[q] = base;
}

// ---------------------------------------------------------------- accumulate M (no atomics)
// thread (ql, c) exclusively owns M[ql, :, c]; plain LDS RMW; 4-entry chunks with
// next-chunk loads issued before current chunk's RMW chain (manual 2-stage pipeline)
template<int C2, int QB, int TPB, bool STAGE_LISTS>
__global__ __launch_bounds__(TPB) void accum4(const float* __restrict__ wlist,
                                              const int* __restrict__ plist,
                                              const int* __restrict__ cnt,
                                              const float* __restrict__ feats,
                                              float* __restrict__ Mout) {
  constexpr int Kd = NBIN * C2;
  static_assert(TPB == QB * C2, "TPB must equal QB*C2");
  __shared__ float Ml[QB * Kd];
  __shared__ float wsh[STAGE_LISTS ? QB*512 : 4];
  __shared__ int   psh[STAGE_LISTS ? QB*512 : 4];
  __shared__ int   csh[QB];
  const int t = threadIdx.x;
  const int q0 = blockIdx.x * QB;
  for (int i = t; i < QB*Kd; i += TPB) Ml[i] = 0.0f;
  if (t < QB) csh[t] = (q0 + t < BN) ? cnt[q0 + t] : 0;
  __syncthreads();
  if (STAGE_LISTS) {
    for (int i = t; i < QB*128; i += TPB) {
      int qs = i >> 7, j = i & 127;
      if (j*4 < csh[qs]) {
        ((float4*)(wsh + qs*512))[j] = ((const float4*)(wlist + (size_t)(q0+qs)*512))[j];
        ((int4*)(psh + qs*512))[j]   = ((const int4*)(plist + (size_t)(q0+qs)*512))[j];
      }
    }
    __syncthreads();
  }
  const int ql = t / C2, c = t % C2;
  const int q = q0 + ql;
  const int nnz = csh[ql];
  float* M = Ml + ql*Kd + c;
  const float* wls; const int* pls;
  if (STAGE_LISTS) { wls = wsh + ql*512; pls = psh + ql*512; }
  else { wls = wlist + (size_t)q*512; pls = plist + (size_t)q*512; }
  const float* fb = feats + (size_t)(q >> 9) * 512 * C2 + c;

  if (nnz > 0) {
    float wA[4], fA[4]; int kA[4];
    float wB[4], fB[4]; int kB[4];
    // prologue: load chunk 0
    #pragma unroll
    for (int j = 0; j < 4; ++j) {
      int idx = j;
      bool v = idx < nnz;
      float w = v ? wls[idx] : 0.0f;
      int p = v ? pls[idx] : 0;
      wA[j] = w; kA[j] = (p & 63) * C2;
      fA[j] = fb[(p >> 6) * C2];
    }
    for (int base = 0; base < nnz; base += 4) {
      if (base + 4 < nnz) {
        #pragma unroll
        for (int j = 0; j < 4; ++j) {
          int idx = base + 4 + j;
          bool v = idx < nnz;
          float w = v ? wls[idx] : 0.0f;
          int p = v ? pls[idx] : 0;
          wB[j] = w; kB[j] = (p & 63) * C2;
          fB[j] = fb[(p >> 6) * C2];
        }
      }
      #pragma unroll
      for (int j = 0; j < 4; ++j) M[kA[j]] += wA[j] * fA[j];
      #pragma unroll
      for (int j = 0; j < 4; ++j) { wA[j] = wB[j]; kA[j] = kB[j]; fA[j] = fB[j]; }
    }
  }
  __syncthreads();
  // write-out: QB rows are contiguous in both Ml and Mout
  float4* dst = (float4*)(Mout + (size_t)q0 * Kd);
  const float4* src4 = (const float4*)Ml;
  const int lim = (q0 + QB <= BN) ? (QB*Kd/4) : ((BN - q0) * (Kd/4));
  for (int i = t; i < lim; i += TPB) dst[i] = src4[i];
}

// ---------------------------------------------------------------- tiled fp32 GEMM with k-split
template<int CT>
__global__ __launch_bounds__(256) void gemm_tiled(const float* __restrict__ A,
                                                  const float* __restrict__ B,
                                                  float* __restrict__ G, int Kdim, int kps) {
  __shared__ float At[16][64];
  __shared__ float Bt[16][CT];
  const int t = threadIdx.x;
  const int row0 = blockIdx.x * 64;
  const int kbeg = blockIdx.y * kps;
  constexpr int CQ = CT / 4;
  constexpr int RGN = 256 / CQ;
  constexpr int RPT = 64 / RGN;
  const int cq = t % CQ;
  const int rg = t / CQ;
  float acc[RPT][4];
  #pragma unroll
  for (int r = 0; r < RPT; ++r)
    for (int cc = 0; cc < 4; ++cc) acc[r][cc] = 0.0f;
  const int arow = t >> 2, akq = t & 3;
  for (int kt = 0; kt < kps; kt += 16) {
    const int k0 = kbeg + kt;
    float4 av4 = *(const float4*)(A + (size_t)(row0 + arow) * Kdim + (k0 + akq*4));
    At[akq*4+0][arow] = av4.x;
    At[akq*4+1][arow] = av4.y;
    At[akq*4+2][arow] = av4.z;
    At[akq*4+3][arow] = av4.w;
    if (CT == 64) {
      int kk = t >> 4, col = (t & 15) * 4;
      *(float4*)&Bt[kk][col] = *(const float4*)(B + (size_t)(k0+kk)*CT + col);
    } else if (t < 128) {
      int kk = t >> 3, col = (t & 7) * 4;
      *(float4*)&Bt[kk][col] = *(const float4*)(B + (size_t)(k0+kk)*CT + col);
    }
    __syncthreads();
    #pragma unroll
    for (int kk = 0; kk < 16; ++kk) {
      float4 bv = *(const float4*)&Bt[kk][cq*4];
      if (RPT == 4) {
        float4 a4 = *(const float4*)&At[kk][rg*4];
        acc[0][0] += a4.x*bv.x; acc[0][1] += a4.x*bv.y; acc[0][2] += a4.x*bv.z; acc[0][3] += a4.x*bv.w;
        acc[1][0] += a4.y*bv.x; acc[1][1] += a4.y*bv.y; acc[1][2] += a4.y*bv.z; acc[1][3] += a4.y*bv.w;
        acc[2][0] += a4.z*bv.x; acc[2][1] += a4.z*bv.y; acc[2][2] += a4.z*bv.z; acc[2][3] += a4.z*bv.w;
        acc[3][0] += a4.w*bv.x; acc[3][1] += a4.w*bv.y; acc[3][2] += a4.w*bv.z; acc[3][3] += a4.w*bv.w;
      } else {
        float2 a2 = *(const float2*)&At[kk][rg*2];
        acc[0][0] += a2.x*bv.x; acc[0][1] += a2.x*bv.y; acc[0][2] += a2.x*bv.z; acc[0][3] += a2.x*bv.w;
        acc[1][0] += a2.y*bv.x; acc[1][1] += a2.y*bv.y; acc[1][2] += a2.y*bv.z; acc[1][3] += a2.y*bv.w;
      }
    }
    __syncthreads();
  }
  const size_t zoff = (size_t)blockIdx.y * BN;
  for (int r = 0; r < RPT; ++r) {
    int row = row0 + rg*RPT + r;
    float* gp = G + (zoff + row) * CT + cq*4;
    gp[0] = acc[r][0]; gp[1] = acc[r][1]; gp[2] = acc[r][2]; gp[3] = acc[r][3];
  }
}

// ---------------------------------------------------------------- thin GEMM for layer4 (2 cols)
__global__ __launch_bounds__(256) void gemm_thin2(const float* __restrict__ M,
                                                  const float* __restrict__ K2,
                                                  float* __restrict__ out) {
  int lane = threadIdx.x & 63;
  int wv = threadIdx.x >> 6;
  int row = blockIdx.x * 4 + wv;
  const float* Ar = M + (size_t)row * 3072;
  float a0 = 0.0f, a1 = 0.0f;
  for (int k = lane; k < 3072; k += 64) {
    float av = Ar[k];
    a0 += av * K2[k*2];
    a1 += av * K2[k*2+1];
  }
  for (int off = 32; off > 0; off >>= 1) {
    a0 += __shfl_down(a0, off);
    a1 += __shfl_down(a1, off);
  }
  if (lane == 0) { out[row*2] = a0; out[row*2+1] = a1; }
}

// ---------------------------------------------------------------- stage-0 epilogue
__global__ void epilogue0(const float* __restrict__ Gpf, const float* __restrict__ Gpo,
                          const float* __restrict__ F0, const float* __restrict__ Adf,
                          const float* __restrict__ Bdf, float* __restrict__ in1) {
  int idx = blockIdx.x * blockDim.x + threadIdx.x;  // q*48+ch
  if (idx >= BN*48) return;
  int ch = idx % 48, q = idx / 48;
  float x = 0.0f, y = 0.0f;
  if (ch < 16) {
    for (int sp = 0; sp < 6; ++sp) {
      size_t base = ((size_t)sp*BN + q)*32 + ch*2;
      x += Gpo[base]; y += Gpo[base+1];
    }
  } else if (ch < 32) {
    int o = ch - 16;
    for (int sp = 0; sp < 8; ++sp) {
      size_t base = ((size_t)sp*BN + q)*32 + o*2;
      x += Gpf[base]; y += Gpf[base+1];
    }
  } else {
    int o = ch - 32;
    const float* f = F0 + (size_t)q*48;
    for (int i = 0; i < 20; ++i) {
      float fx = f[i*2], fy = f[i*2+1];
      float Av = Adf[o*20+i], Bv = Bdf[o*20+i];
      x += Av*fx - Bv*fy;
      y += Av*fy + Bv*fx;
    }
  }
  float m = x*x + y*y + 1e-6f;
  float sc = fmaxf(m - 0.2f, 0.0f) / m;
  in1[(size_t)idx*2]   = x * sc;
  in1[(size_t)idx*2+1] = y * sc;
}

// ---------------------------------------------------------------- layer epilogue (layers 1-3)
__global__ void epilogueL(const float* __restrict__ Gp, int SPLIT,
                          const float* __restrict__ inPrev, int I,
                          const float* __restrict__ Ad, const float* __restrict__ Bd,
                          const float* __restrict__ prevOut, int doRes,
                          float* __restrict__ outCur, float* __restrict__ inNext) {
  int idx = blockIdx.x * blockDim.x + threadIdx.x;  // q*32+o
  if (idx >= BN*32) return;
  int o = idx % 32, q = idx / 32;
  float x = 0.0f, y = 0.0f;
  for (int sp = 0; sp < SPLIT; ++sp) {
    size_t base = ((size_t)sp*BN + q)*64 + o*2;
    x += Gp[base]; y += Gp[base+1];
  }
  const float* f = inPrev + (size_t)q * I * 2;
  for (int i = 0; i < I; ++i) {
    float fx = f[i*2], fy = f[i*2+1];
    float Av = Ad[o*I+i], Bv = Bd[o*I+i];
    x += Av*fx - Bv*fy;
    y += Av*fy + Bv*fx;
  }
  if (doRes) {
    x += prevOut[(size_t)idx*2];
    y += prevOut[(size_t)idx*2+1];
  }
  outCur[(size_t)idx*2]   = x;
  outCur[(size_t)idx*2+1] = y;
  float m = x*x + y*y + 1e-6f;
  float sc = fmaxf(m - 0.2f, 0.0f) / m;
  inNext[(size_t)idx*2]   = x * sc;
  inNext[(size_t)idx*2+1] = y * sc;
}

// ---------------------------------------------------------------- final
__global__ void final_kernel(const float* __restrict__ conv4, const float* __restrict__ in4,
                             const float* __restrict__ Ad4, const float* __restrict__ Bd4,
                             const float* __restrict__ p1, const float* __restrict__ p0,
                             float* __restrict__ dout) {
  int q = blockIdx.x * blockDim.x + threadIdx.x;
  if (q >= BN) return;
  float x = conv4[q*2], y = conv4[q*2+1];
  const float* f = in4 + (size_t)q * 64;
  for (int i = 0; i < 32; ++i) {
    float fx = f[i*2], fy = f[i*2+1];
    float Av = Ad4[i], Bv = Bd4[i];
    x += Av*fx - Bv*fy;
    y += Av*fy + Bv*fx;
  }
  float cx = x / 128.0f, cy = y / 128.0f;
  float px = p1[q*2] + cx, py = p1[q*2+1] + cy;
  float vx = (px - p0[q*2]) / 0.1f;
  float vy = (py - p0[q*2+1]) / 0.1f;
  dout[q*2] = px; dout[q*2+1] = py;
  dout[4096 + q*2] = vx; dout[4096 + q*2+1] = vy;
}

// ---------------------------------------------------------------- launch
extern "C" void kernel_launch(void* const* d_in, const int* in_sizes, int n_in,
                              void* d_out, int out_size, void* d_ws, size_t ws_size,
                              hipStream_t stream) {
  (void)in_sizes; (void)n_in; (void)out_size; (void)ws_size;
  const float* v0_enc = (const float*)d_in[1];
  const float* p0     = (const float*)d_in[2];
  const float* v0     = (const float*)d_in[3];
  const float* a      = (const float*)d_in[4];
  const float* other  = (const float*)d_in[5];
  const float* box    = (const float*)d_in[6];
  const float* boxf   = (const float*)d_in[7];
  const float* fmask  = (const float*)d_in[8];
  const float* bmask  = (const float*)d_in[9];
  const float* Wcf = (const float*)d_in[10];
  const float* Wco = (const float*)d_in[11];
  const float* Adf = (const float*)d_in[12];
  const float* Bdf = (const float*)d_in[13];
  const float* Wc1 = (const float*)d_in[14];
  const float* Ad1 = (const float*)d_in[15];
  const float* Bd1 = (const float*)d_in[16];
  const float* Wc2 = (const float*)d_in[17];
  const float* Ad2 = (const float*)d_in[18];
  const float* Bd2 = (const float*)d_in[19];
  const float* Wc3 = (const float*)d_in[20];
  const float* Ad3 = (const float*)d_in[21];
  const float* Bd3 = (const float*)d_in[22];
  const float* Wc4 = (const float*)d_in[23];
  const float* Ad4 = (const float*)d_in[24];
  const float* Bd4 = (const float*)d_in[25];

  float* ws = (float*)d_ws;
  float* P1    = ws + 0;          // 4096
  float* F0    = ws + 4096;       // 98304  (stride 48, padded)
  float* K2CF  = ws + 102400;     // 73728  (2304 x 32)
  float* K2CO  = ws + 176128;     // 3072   (96 x 32)
  float* K2C1  = ws + 179200;     // 294912 (4608 x 64)
  float* K2C2  = ws + 474112;     // 196608 (3072 x 64)
  float* K2C3  = ws + 670720;     // 196608
  float* K2C4  = ws + 867328;     // 6144   (3072 x 2)
  float* WFl   = ws + 873472;     // 1048576
  int*   PFl   = (int*)(ws + 1922048);   // 1048576
  int*   CNTF  = (int*)(ws + 2970624);   // 2048
  int*   CNTO  = (int*)(ws + 2972672);   // 2048
  float* IN1   = ws + 2974720;    // 196608 (2048 x 96)
  float* IN2   = ws + 3171328;    // 131072
  float* IN3   = ws + 3302400;    // 131072
  float* IN4   = ws + 3433472;    // 131072
  float* OUTA  = ws + 3564544;    // 131072
  float* OUTB  = ws + 3695616;    // 131072
  float* C4OUT = ws + 3826688;    // 4096
  float* MO    = ws + 3830784;    // 196608 (box M: 2048 x 96)
  float* GPF   = ws + 4027392;    // 524288 (8 x 2048 x 32)
  float* GPO   = ws + 4551680;    // 393216 (6 x 2048 x 32)
  float* GPART = ws + 4027392;    // 1048576 (8 x 2048 x 64) reuses GPF/GPO region
  float* MBUF  = ws + 5075968;    // 9437184 (max 2048 x 4608)
  float* WOl   = MBUF + 7340032;  // 1048576 (dead before layer1 M reaches here)
  int*   POl   = (int*)(MBUF + 8388608);  // 1048576

  prep_kernel<<<8, 256, 0, stream>>>(p0, v0, a, other, v0_enc, P1, F0);
  steer_kernel<<<(48*16*24 + 255)/256, 256, 0, stream>>>(Wcf, K2CF, 16, 20, 24);
  steer_kernel<<<(48*16*1  + 255)/256, 256, 0, stream>>>(Wco, K2CO, 16, 1, 1);
  steer_kernel<<<(48*32*48 + 255)/256, 256, 0, stream>>>(Wc1, K2C1, 32, 48, 48);
  steer_kernel<<<(48*32*32 + 255)/256, 256, 0, stream>>>(Wc2, K2C2, 32, 32, 32);
  steer_kernel<<<(48*32*32 + 255)/256, 256, 0, stream>>>(Wc3, K2C3, 32, 32, 32);
  steer_kernel<<<(48*1*32  + 255)/256, 256, 0, stream>>>(Wc4, K2C4, 1, 32, 32);
  pairs_compact<<<512, 256, 0, stream>>>(P1, P1, fmask, WFl, PFl, CNTF);
  pairs_compact<<<512, 256, 0, stream>>>(P1, box, bmask, WOl, POl, CNTO);

  // stage 0: box conv (C2=2, QB=64, lists read from global), then fluid conv (C2=48)
  accum4<2, 64, 128, false><<<32, 128, 0, stream>>>(WOl, POl, CNTO, boxf, MO);
  gemm_tiled<32><<<dim3(32, 6), 256, 0, stream>>>(MO, K2CO, GPO, 96, 16);
  accum4<48, 4, 192, true><<<512, 192, 0, stream>>>(WFl, PFl, CNTF, F0, MBUF);
  gemm_tiled<32><<<dim3(32, 8), 256, 0, stream>>>(MBUF, K2CF, GPF, 2304, 288);
  epilogue0<<<384, 256, 0, stream>>>(GPF, GPO, F0, Adf, Bdf, IN1);

  // layer 1: I=48 -> O=32
  accum4<96, 2, 192, true><<<1024, 192, 0, stream>>>(WFl, PFl, CNTF, IN1, MBUF);
  gemm_tiled<64><<<dim3(32, 8), 256, 0, stream>>>(MBUF, K2C1, GPART, 4608, 576);
  epilogueL<<<256, 256, 0, stream>>>(GPART, 8, IN1, 48, Ad1, Bd1, nullptr, 0, OUTA, IN2);

  // layer 2: I=32 -> O=32, residual
  accum4<64, 3, 192, true><<<683, 192, 0, stream>>>(WFl, PFl, CNTF, IN2, MBUF);
  gemm_tiled<64><<<dim3(32, 8), 256, 0, stream>>>(MBUF, K2C2, GPART, 3072, 384);
  epilogueL<<<256, 256, 0, stream>>>(GPART, 8, IN2, 32, Ad2, Bd2, OUTA, 1, OUTB, IN3);

  // layer 3: I=32 -> O=32, residual
  accum4<64, 3, 192, true><<<683, 192, 0, stream>>>(WFl, PFl, CNTF, IN3, MBUF);
  gemm_tiled<64><<<dim3(32, 8), 256, 0, stream>>>(MBUF, K2C3, GPART, 3072, 384);
  epilogueL<<<256, 256, 0, stream>>>(GPART, 8, IN3, 32, Ad3, Bd3, OUTB, 1, OUTA, IN4);

  // layer 4: I=32 -> O=1, then apply correction
  accum4<64, 3, 192, true><<<683, 192, 0, stream>>>(WFl, PFl, CNTF, IN4, MBUF);
  gemm_thin2<<<512, 256, 0, stream>>>(MBUF, K2C4, C4OUT);
  final_kernel<<<8, 256, 0, stream>>>(C4OUT, IN4, Ad4, Bd4, P1, p0, (float*)d_out);
}